// Round 1
// baseline (788.006 us; speedup 1.0000x reference)
//
#include <hip/hip_runtime.h>
#include <hip/hip_bf16.h>
#include <math.h>

// Dims (compile-time constants for this problem)
#define Bb 2
#define Tt 1024
#define Dd 512
#define Hh 8
#define Kk 64
#define Vv 64
#define BT (Bb*Tt)          // 2048
#define HK (Hh*Kk)          // 512

// hyperparams
#define B1c 0.9f
#define B2c 0.999f
#define LRc 1e-3f
#define SCALEc 0.125f       // 64^-0.5

// ---------------------------------------------------------------------------
// fp32 tiled GEMM: C[M,N] = A[M,K] @ W[K,N], M=2048, N=512, K=512
// BM=BN=64, BK=16, 256 threads, 4x4 micro-tile per thread.
// ---------------------------------------------------------------------------
__device__ __forceinline__ void gemm_body(const float* __restrict__ A,
                                          const float* __restrict__ Bm,
                                          float* __restrict__ C) {
  constexpr int N = 512, Kd = 512;
  __shared__ float As[16][68];   // [k][m], padded (68*4B = 272B row, 16B aligned)
  __shared__ float Bs[16][68];   // [k][n]
  const int tid = threadIdx.x;
  const int bm = blockIdx.x * 64;
  const int bn = blockIdx.y * 64;
  const int tr = (tid >> 4) << 2;       // 0..60
  const int tc = (tid & 15) << 2;       // 0..60
  const int ar = tid >> 2;              // A tile row 0..63
  const int ak = (tid & 3) << 2;        // A tile k-col {0,4,8,12}
  const int bk = tid >> 4;              // B tile k-row 0..15
  const int bn4 = (tid & 15) << 2;      // B tile n-col
  float acc[4][4] = {};
  for (int k0 = 0; k0 < Kd; k0 += 16) {
    float4 av = *(const float4*)(A + (size_t)(bm + ar) * Kd + k0 + ak);
    float4 bv = *(const float4*)(Bm + (size_t)(k0 + bk) * N + bn + bn4);
    __syncthreads();
    As[ak + 0][ar] = av.x;
    As[ak + 1][ar] = av.y;
    As[ak + 2][ar] = av.z;
    As[ak + 3][ar] = av.w;
    *(float4*)&Bs[bk][bn4] = bv;
    __syncthreads();
#pragma unroll
    for (int kk = 0; kk < 16; ++kk) {
      float4 a = *(const float4*)&As[kk][tr];
      float4 b = *(const float4*)&Bs[kk][tc];
      const float ai[4] = {a.x, a.y, a.z, a.w};
      const float bj[4] = {b.x, b.y, b.z, b.w};
#pragma unroll
      for (int i = 0; i < 4; ++i)
#pragma unroll
        for (int j = 0; j < 4; ++j) acc[i][j] += ai[i] * bj[j];
    }
  }
#pragma unroll
  for (int i = 0; i < 4; ++i) {
    float4 o4 = {acc[i][0], acc[i][1], acc[i][2], acc[i][3]};
    *(float4*)(C + (size_t)(bm + tr + i) * N + bn + tc) = o4;
  }
}

__global__ __launch_bounds__(256) void gemm3_kernel(
    const float* __restrict__ x,
    const float* __restrict__ Wq, const float* __restrict__ Wk,
    const float* __restrict__ Wv,
    float* __restrict__ qp, float* __restrict__ kp, float* __restrict__ vp) {
  const float* W; float* Cp;
  if (blockIdx.z == 0)      { W = Wq; Cp = qp; }
  else if (blockIdx.z == 1) { W = Wk; Cp = kp; }
  else                      { W = Wv; Cp = vp; }
  gemm_body(x, W, Cp);
}

__global__ __launch_bounds__(256) void gemm1_kernel(
    const float* __restrict__ A, const float* __restrict__ W,
    float* __restrict__ C) {
  gemm_body(A, W, C);
}

// ---------------------------------------------------------------------------
// beta = sigmoid(x @ Wb), Wb:[512,8] -> beta:[B*T,8]
// ---------------------------------------------------------------------------
__global__ __launch_bounds__(256) void beta_kernel(const float* __restrict__ x,
                                                   const float* __restrict__ Wb,
                                                   float* __restrict__ beta) {
  int gid = blockIdx.x * blockDim.x + threadIdx.x;  // 0 .. 16383
  int bt = gid >> 3, h = gid & 7;
  const float* xr = x + (size_t)bt * Dd;
  float s = 0.f;
  for (int d = 0; d < Dd; ++d) s += xr[d] * Wb[d * Hh + h];
  beta[gid] = 1.f / (1.f + expf(-s));
}

// ---------------------------------------------------------------------------
// causal depthwise conv(4) + SiLU (+ optional L2 norm over K, + scale for q)
// one wave per (b,t,h); lane = channel-within-head
// mode 0: q (norm + *SCALE), mode 1: k (norm), mode 2: v (no norm)
// ---------------------------------------------------------------------------
__global__ __launch_bounds__(256) void conv_kernel(
    const float* __restrict__ qp, const float* __restrict__ kp,
    const float* __restrict__ vp,
    const float* __restrict__ cwq, const float* __restrict__ cwk,
    const float* __restrict__ cwv,
    float* __restrict__ qc, float* __restrict__ kc, float* __restrict__ vc) {
  const int mode = blockIdx.z;
  const float* pre; const float* cw; float* post;
  if (mode == 0)      { pre = qp; cw = cwq; post = qc; }
  else if (mode == 1) { pre = kp; cw = cwk; post = kc; }
  else                { pre = vp; cw = cwv; post = vc; }

  const int idx = blockIdx.x * 4 + (threadIdx.x >> 6);   // (b,t,h) id, 0..16383
  const int lane = threadIdx.x & 63;
  const int b = idx >> 13;           // /(T*H)
  const int th = idx & 8191;
  const int t = th >> 3;
  const int h = th & 7;
  const int ch = h * 64 + lane;

  float y = 0.f;
#pragma unroll
  for (int i = 0; i < 4; ++i) {
    int tt = t + i - 3;
    if (tt >= 0)
      y += pre[((size_t)(b * Tt + tt)) * HK + ch] * cw[ch * 4 + i];
  }
  // SiLU
  y = y / (1.f + expf(-y));
  if (mode < 2) {
    float ss = y * y;
#pragma unroll
    for (int off = 32; off; off >>= 1) ss += __shfl_xor(ss, off, 64);
    y *= rsqrtf(ss + 1e-6f);
    if (mode == 0) y *= SCALEc;
  }
  post[((size_t)(b * Tt + t)) * HK + ch] = y;
}

// ---------------------------------------------------------------------------
// sequential IVON delta-rule scan.
// One wave per output column (b,h,v); lane = k. State S,h,g in 3 VGPRs/lane.
// grid = B*H*V/4 = 256 blocks of 4 waves (4 consecutive v per block).
// ---------------------------------------------------------------------------
__global__ __launch_bounds__(256) void scan_kernel(
    const float* __restrict__ qc, const float* __restrict__ kc,
    const float* __restrict__ vc, const float* __restrict__ beta,
    float* __restrict__ o) {
  const int lane = threadIdx.x & 63;
  const int wave = threadIdx.x >> 6;
  const int bh = blockIdx.x >> 4;      // 0..15
  const int vblk = blockIdx.x & 15;
  const int b = bh >> 3, h = bh & 7;
  const int v = vblk * 4 + wave;

  const size_t base = ((size_t)b * Tt) * HK + h * 64;
  const float* kptr = kc + base + lane;
  const float* qptr = qc + base + lane;
  const float* vptr = vc + base + v;
  const float* bptr = beta + ((size_t)b * Tt) * Hh + h;
  float* optr = o + base + v;

  float S = 0.f, hs = 0.f, g = 0.f;
  for (int t = 0; t < Tt; ++t) {
    const float kv = kptr[(size_t)t * HK];
    const float qv = qptr[(size_t)t * HK];
    const float vv = vptr[(size_t)t * HK];
    const float bt = bptr[(size_t)t * Hh];

    float pred = kv * S;
#pragma unroll
    for (int off = 32; off; off >>= 1) pred += __shfl_xor(pred, off, 64);

    const float grad = kv * (pred - vv);
    g = B1c * g + (1.f - B1c) * grad;
    hs = B2c * hs + (1.f - B2c) * grad * grad;
    S -= (LRc * bt) * g * __builtin_amdgcn_rcpf(hs + 1.f);

    float ov = qv * S;
#pragma unroll
    for (int off = 32; off; off >>= 1) ov += __shfl_xor(ov, off, 64);
    if (lane == 0) optr[(size_t)t * HK] = ov;
  }
}

// ---------------------------------------------------------------------------
// RMSNorm over V=64 (in-place), * rms_w
// ---------------------------------------------------------------------------
__global__ __launch_bounds__(256) void rmsnorm_kernel(float* __restrict__ o,
                                                      const float* __restrict__ rmsw) {
  const int idx = blockIdx.x * 4 + (threadIdx.x >> 6);  // (b,t,h), 0..16383
  const int lane = threadIdx.x & 63;
  float* p = o + (size_t)idx * 64;
  float y = p[lane];
  float ss = y * y;
#pragma unroll
  for (int off = 32; off; off >>= 1) ss += __shfl_xor(ss, off, 64);
  y = y * rsqrtf(ss * (1.f / 64.f) + 1e-5f) * rmsw[lane];
  p[lane] = y;
}

// ---------------------------------------------------------------------------
extern "C" void kernel_launch(void* const* d_in, const int* in_sizes, int n_in,
                              void* d_out, int out_size, void* d_ws, size_t ws_size,
                              hipStream_t stream) {
  const float* x    = (const float*)d_in[0];
  const float* Wq   = (const float*)d_in[1];
  const float* Wk   = (const float*)d_in[2];
  const float* Wv   = (const float*)d_in[3];
  const float* Wb   = (const float*)d_in[4];
  const float* cwq  = (const float*)d_in[5];
  const float* cwk  = (const float*)d_in[6];
  const float* cwv  = (const float*)d_in[7];
  const float* rmsw = (const float*)d_in[8];
  const float* Wo   = (const float*)d_in[9];
  float* out = (float*)d_out;
  float* ws  = (float*)d_ws;

  const size_t SZ = (size_t)BT * HK;   // 1,048,576 floats
  float* qp   = ws;            // pre-conv q   (later reused as scan output)
  float* kp   = ws + 1 * SZ;
  float* vp   = ws + 2 * SZ;
  float* qc   = ws + 3 * SZ;
  float* kc   = ws + 4 * SZ;
  float* vc   = ws + 5 * SZ;
  float* beta = ws + 6 * SZ;   // 16384 floats
  float* on   = qp;            // scan output / rmsnorm in-place (qp is dead then)

  // 1. projections q,k,v
  gemm3_kernel<<<dim3(BT / 64, HK / 64, 3), 256, 0, stream>>>(x, Wq, Wk, Wv, qp, kp, vp);
  // 2. beta
  beta_kernel<<<dim3(BT * Hh / 256), 256, 0, stream>>>(x, Wb, beta);
  // 3. conv + silu + l2norm
  conv_kernel<<<dim3(Bb * Tt * Hh / 4, 1, 3), 256, 0, stream>>>(
      qp, kp, vp, cwq, cwk, cwv, qc, kc, vc);
  // 4. sequential scan
  scan_kernel<<<dim3(Bb * Hh * (Vv / 4)), 256, 0, stream>>>(qc, kc, vc, beta, on);
  // 5. RMSNorm (in-place)
  rmsnorm_kernel<<<dim3(Bb * Tt * Hh / 4), 256, 0, stream>>>(on, rmsw);
  // 6. output projection
  gemm1_kernel<<<dim3(BT / 64, HK / 64, 1), 256, 0, stream>>>(on, Wo, out);
}

// Round 2
// 420.421 us; speedup vs baseline: 1.8743x; 1.8743x over previous
//
#include <hip/hip_runtime.h>
#include <hip/hip_bf16.h>
#include <math.h>

// Dims (compile-time constants for this problem)
#define Bb 2
#define Tt 1024
#define Dd 512
#define Hh 8
#define Kk 64
#define Vv 64
#define BT (Bb*Tt)          // 2048
#define HK (Hh*Kk)          // 512

// hyperparams
#define B1c 0.9f
#define B2c 0.999f
#define LRc 1e-3f
#define SCALEc 0.125f       // 64^-0.5

// ---------------------------------------------------------------------------
// fp32 tiled GEMM: C[M,N] = A[M,K] @ W[K,N], M=2048, N=512, K=512
// BM=BN=64, BK=16, 256 threads, 4x4 micro-tile per thread.
// ---------------------------------------------------------------------------
__device__ __forceinline__ void gemm_body(const float* __restrict__ A,
                                          const float* __restrict__ Bm,
                                          float* __restrict__ C) {
  constexpr int N = 512, Kd = 512;
  __shared__ float As[16][68];   // [k][m], padded
  __shared__ float Bs[16][68];   // [k][n]
  const int tid = threadIdx.x;
  const int bm = blockIdx.x * 64;
  const int bn = blockIdx.y * 64;
  const int tr = (tid >> 4) << 2;       // 0..60
  const int tc = (tid & 15) << 2;       // 0..60
  const int ar = tid >> 2;              // A tile row 0..63
  const int ak = (tid & 3) << 2;        // A tile k-col {0,4,8,12}
  const int bk = tid >> 4;              // B tile k-row 0..15
  const int bn4 = (tid & 15) << 2;      // B tile n-col
  float acc[4][4] = {};
  for (int k0 = 0; k0 < Kd; k0 += 16) {
    float4 av = *(const float4*)(A + (size_t)(bm + ar) * Kd + k0 + ak);
    float4 bv = *(const float4*)(Bm + (size_t)(k0 + bk) * N + bn + bn4);
    __syncthreads();
    As[ak + 0][ar] = av.x;
    As[ak + 1][ar] = av.y;
    As[ak + 2][ar] = av.z;
    As[ak + 3][ar] = av.w;
    *(float4*)&Bs[bk][bn4] = bv;
    __syncthreads();
#pragma unroll
    for (int kk = 0; kk < 16; ++kk) {
      float4 a = *(const float4*)&As[kk][tr];
      float4 b = *(const float4*)&Bs[kk][tc];
      const float ai[4] = {a.x, a.y, a.z, a.w};
      const float bj[4] = {b.x, b.y, b.z, b.w};
#pragma unroll
      for (int i = 0; i < 4; ++i)
#pragma unroll
        for (int j = 0; j < 4; ++j) acc[i][j] += ai[i] * bj[j];
    }
  }
#pragma unroll
  for (int i = 0; i < 4; ++i) {
    float4 o4 = {acc[i][0], acc[i][1], acc[i][2], acc[i][3]};
    *(float4*)(C + (size_t)(bm + tr + i) * N + bn + tc) = o4;
  }
}

__global__ __launch_bounds__(256) void gemm3_kernel(
    const float* __restrict__ x,
    const float* __restrict__ Wq, const float* __restrict__ Wk,
    const float* __restrict__ Wv,
    float* __restrict__ qp, float* __restrict__ kp, float* __restrict__ vp) {
  const float* W; float* Cp;
  if (blockIdx.z == 0)      { W = Wq; Cp = qp; }
  else if (blockIdx.z == 1) { W = Wk; Cp = kp; }
  else                      { W = Wv; Cp = vp; }
  gemm_body(x, W, Cp);
}

__global__ __launch_bounds__(256) void gemm1_kernel(
    const float* __restrict__ A, const float* __restrict__ W,
    float* __restrict__ C) {
  gemm_body(A, W, C);
}

// ---------------------------------------------------------------------------
// beta = sigmoid(x @ Wb), Wb:[512,8] -> beta:[B*T,8]
// ---------------------------------------------------------------------------
__global__ __launch_bounds__(256) void beta_kernel(const float* __restrict__ x,
                                                   const float* __restrict__ Wb,
                                                   float* __restrict__ beta) {
  int gid = blockIdx.x * blockDim.x + threadIdx.x;  // 0 .. 16383
  int bt = gid >> 3, h = gid & 7;
  const float* xr = x + (size_t)bt * Dd;
  float s = 0.f;
  for (int d = 0; d < Dd; ++d) s += xr[d] * Wb[d * Hh + h];
  beta[gid] = 1.f / (1.f + expf(-s));
}

// ---------------------------------------------------------------------------
// causal depthwise conv(4) + SiLU (+ optional L2 norm over K, + scale for q)
// ---------------------------------------------------------------------------
__global__ __launch_bounds__(256) void conv_kernel(
    const float* __restrict__ qp, const float* __restrict__ kp,
    const float* __restrict__ vp,
    const float* __restrict__ cwq, const float* __restrict__ cwk,
    const float* __restrict__ cwv,
    float* __restrict__ qc, float* __restrict__ kc, float* __restrict__ vc) {
  const int mode = blockIdx.z;
  const float* pre; const float* cw; float* post;
  if (mode == 0)      { pre = qp; cw = cwq; post = qc; }
  else if (mode == 1) { pre = kp; cw = cwk; post = kc; }
  else                { pre = vp; cw = cwv; post = vc; }

  const int idx = blockIdx.x * 4 + (threadIdx.x >> 6);   // (b,t,h) id, 0..16383
  const int lane = threadIdx.x & 63;
  const int b = idx >> 13;           // /(T*H)
  const int th = idx & 8191;
  const int t = th >> 3;
  const int h = th & 7;
  const int ch = h * 64 + lane;

  float y = 0.f;
#pragma unroll
  for (int i = 0; i < 4; ++i) {
    int tt = t + i - 3;
    if (tt >= 0)
      y += pre[((size_t)(b * Tt + tt)) * HK + ch] * cw[ch * 4 + i];
  }
  // SiLU
  y = y / (1.f + expf(-y));
  if (mode < 2) {
    float ss = y * y;
#pragma unroll
    for (int off = 32; off; off >>= 1) ss += __shfl_xor(ss, off, 64);
    y *= rsqrtf(ss + 1e-6f);
    if (mode == 0) y *= SCALEc;
  }
  post[((size_t)(b * Tt + t)) * HK + ch] = y;
}

// ---------------------------------------------------------------------------
// DPP 16-lane butterfly sum (all 16 lanes of each DPP row end with the total)
// ---------------------------------------------------------------------------
template <int CTRL>
__device__ __forceinline__ float dpp_add(float v) {
  int y = __builtin_amdgcn_update_dpp(0, __float_as_int(v), CTRL, 0xF, 0xF, true);
  return v + __int_as_float(y);
}
__device__ __forceinline__ float reduce16(float x) {
  x = dpp_add<0xB1>(x);   // quad_perm(1,0,3,2)  xor 1
  x = dpp_add<0x4E>(x);   // quad_perm(2,3,0,1)  xor 2
  x = dpp_add<0x141>(x);  // row_half_mirror     (pairs the two quads in each 8)
  x = dpp_add<0x140>(x);  // row_mirror          (pairs the two 8-halves)
  return x;
}

// ---------------------------------------------------------------------------
// sequential IVON delta-rule scan.
// One wave handles 4 v-columns of one (b,h): 64 lanes = 4 v-groups x 16 k-groups,
// each lane holds 4 consecutive k of the S/h/g state for its v-column.
// Reduction over k = 4 local FMAs + 4 DPP adds within a 16-lane row.
// grid: 256 blocks x 64 threads; bid = vq*16 + bh so all 16 waves of a (b,h)
// land on the same XCD (bid % 8 == bh % 8) and share the L2 k/q/v stream.
// ---------------------------------------------------------------------------
#define IVON_STEP(kv, qv, vv, bt, tidx)                                        \
  do {                                                                         \
    float pl = kv.x * S0 + kv.y * S1 + kv.z * S2 + kv.w * S3;                  \
    float pred = reduce16(pl);                                                 \
    float diff = pred - (vv);                                                  \
    float lrb = LRc * (bt);                                                    \
    float gr;                                                                  \
    gr = kv.x * diff; g0 = B1c * g0 + 0.1f * gr;                               \
    h0 = B2c * h0 + 0.001f * (gr * gr);                                        \
    S0 -= lrb * g0 * __builtin_amdgcn_rcpf(h0 + 1.f);                          \
    gr = kv.y * diff; g1 = B1c * g1 + 0.1f * gr;                               \
    h1 = B2c * h1 + 0.001f * (gr * gr);                                        \
    S1 -= lrb * g1 * __builtin_amdgcn_rcpf(h1 + 1.f);                          \
    gr = kv.z * diff; g2 = B1c * g2 + 0.1f * gr;                               \
    h2 = B2c * h2 + 0.001f * (gr * gr);                                        \
    S2 -= lrb * g2 * __builtin_amdgcn_rcpf(h2 + 1.f);                          \
    gr = kv.w * diff; g3 = B1c * g3 + 0.1f * gr;                               \
    h3 = B2c * h3 + 0.001f * (gr * gr);                                        \
    S3 -= lrb * g3 * __builtin_amdgcn_rcpf(h3 + 1.f);                          \
    float ol = qv.x * S0 + qv.y * S1 + qv.z * S2 + qv.w * S3;                  \
    float ov = reduce16(ol);                                                   \
    if (kg == 0) op[(size_t)(tidx)*HK] = ov;                                   \
  } while (0)

__global__ __launch_bounds__(64) void scan_kernel(
    const float* __restrict__ qc, const float* __restrict__ kc,
    const float* __restrict__ vc, const float* __restrict__ beta,
    float* __restrict__ o) {
  const int lane = threadIdx.x;       // 0..63
  const int vg = lane >> 4;           // 0..3  (v within this wave's group of 4)
  const int kg = lane & 15;           // 0..15 (k-group; 4 k per lane)
  const int bid = blockIdx.x;         // 0..255
  const int vq = bid >> 4;            // 0..15
  const int bh = bid & 15;            // same XCD for all vq of this bh
  const int b = bh >> 3, h = bh & 7;
  const int v = vq * 4 + vg;

  const size_t base = ((size_t)b * Tt) * HK + h * 64;
  const float* kp = kc + base + kg * 4;
  const float* qp = qc + base + kg * 4;
  const float* vp = vc + base + v;
  const float* bp = beta + ((size_t)b * Tt) * Hh + h;
  float* op = o + base + v;

  float S0 = 0, S1 = 0, S2 = 0, S3 = 0;
  float h0 = 0, h1 = 0, h2 = 0, h3 = 0;
  float g0 = 0, g1 = 0, g2 = 0, g3 = 0;

  // depth-2 register prefetch, named double buffers (static indexing only)
  float4 kA = *(const float4*)(kp);
  float4 qA = *(const float4*)(qp);
  float  vA = vp[0];
  float  bA = bp[0];
  float4 kB = *(const float4*)(kp + HK);
  float4 qB = *(const float4*)(qp + HK);
  float  vB = vp[HK];
  float  bB = bp[Hh];

  for (int t = 0; t < Tt; t += 2) {
    {
      float4 kv = kA, qv = qA; float vv = vA, bt = bA;
      const int tp = (t + 2 < Tt) ? t + 2 : Tt - 1;
      kA = *(const float4*)(kp + (size_t)tp * HK);
      qA = *(const float4*)(qp + (size_t)tp * HK);
      vA = vp[(size_t)tp * HK];
      bA = bp[(size_t)tp * Hh];
      IVON_STEP(kv, qv, vv, bt, t);
    }
    {
      float4 kv = kB, qv = qB; float vv = vB, bt = bB;
      const int tp = (t + 3 < Tt) ? t + 3 : Tt - 1;
      kB = *(const float4*)(kp + (size_t)tp * HK);
      qB = *(const float4*)(qp + (size_t)tp * HK);
      vB = vp[(size_t)tp * HK];
      bB = bp[(size_t)tp * Hh];
      IVON_STEP(kv, qv, vv, bt, t + 1);
    }
  }
}

// ---------------------------------------------------------------------------
// RMSNorm over V=64 (in-place), * rms_w
// ---------------------------------------------------------------------------
__global__ __launch_bounds__(256) void rmsnorm_kernel(float* __restrict__ o,
                                                      const float* __restrict__ rmsw) {
  const int idx = blockIdx.x * 4 + (threadIdx.x >> 6);  // (b,t,h), 0..16383
  const int lane = threadIdx.x & 63;
  float* p = o + (size_t)idx * 64;
  float y = p[lane];
  float ss = y * y;
#pragma unroll
  for (int off = 32; off; off >>= 1) ss += __shfl_xor(ss, off, 64);
  y = y * rsqrtf(ss * (1.f / 64.f) + 1e-5f) * rmsw[lane];
  p[lane] = y;
}

// ---------------------------------------------------------------------------
extern "C" void kernel_launch(void* const* d_in, const int* in_sizes, int n_in,
                              void* d_out, int out_size, void* d_ws, size_t ws_size,
                              hipStream_t stream) {
  const float* x    = (const float*)d_in[0];
  const float* Wq   = (const float*)d_in[1];
  const float* Wk   = (const float*)d_in[2];
  const float* Wv   = (const float*)d_in[3];
  const float* Wb   = (const float*)d_in[4];
  const float* cwq  = (const float*)d_in[5];
  const float* cwk  = (const float*)d_in[6];
  const float* cwv  = (const float*)d_in[7];
  const float* rmsw = (const float*)d_in[8];
  const float* Wo   = (const float*)d_in[9];
  float* out = (float*)d_out;
  float* ws  = (float*)d_ws;

  const size_t SZ = (size_t)BT * HK;   // 1,048,576 floats
  float* qp   = ws;            // pre-conv q   (later reused as scan output)
  float* kp   = ws + 1 * SZ;
  float* vp   = ws + 2 * SZ;
  float* qc   = ws + 3 * SZ;
  float* kc   = ws + 4 * SZ;
  float* vc   = ws + 5 * SZ;
  float* beta = ws + 6 * SZ;   // 16384 floats
  float* on   = qp;            // scan output / rmsnorm in-place (qp dead then)

  // 1. projections q,k,v
  gemm3_kernel<<<dim3(BT / 64, HK / 64, 3), 256, 0, stream>>>(x, Wq, Wk, Wv, qp, kp, vp);
  // 2. beta
  beta_kernel<<<dim3(BT * Hh / 256), 256, 0, stream>>>(x, Wb, beta);
  // 3. conv + silu + l2norm
  conv_kernel<<<dim3(Bb * Tt * Hh / 4, 1, 3), 256, 0, stream>>>(
      qp, kp, vp, cwq, cwk, cwv, qc, kc, vc);
  // 4. sequential scan (DPP 16-lane reduce, 4 v per wave)
  scan_kernel<<<dim3(Bb * Hh * (Vv / 4) * (Vv / 16) / 4), 64, 0, stream>>>(
      qc, kc, vc, beta, on);
  // 5. RMSNorm (in-place)
  rmsnorm_kernel<<<dim3(Bb * Tt * Hh / 4), 256, 0, stream>>>(on, rmsw);
  // 6. output projection
  gemm1_kernel<<<dim3(BT / 64, HK / 64, 1), 256, 0, stream>>>(on, Wo, out);
}

// Round 3
// 332.986 us; speedup vs baseline: 2.3665x; 1.2626x over previous
//
#include <hip/hip_runtime.h>
#include <hip/hip_bf16.h>
#include <math.h>

// Dims (compile-time constants for this problem)
#define Bb 2
#define Tt 1024
#define Dd 512
#define Hh 8
#define Kk 64
#define Vv 64
#define BT (Bb*Tt)          // 2048
#define HK (Hh*Kk)          // 512

// hyperparams
#define B1c 0.9f
#define B2c 0.999f
#define LRc 1e-3f
#define SCALEc 0.125f       // 64^-0.5

// ---------------------------------------------------------------------------
// fp32 tiled GEMM: C[M,N] = A[M,K] @ W[K,N], M=2048, N=512, K=512
// BM=BN=64, BK=16, 256 threads, 4x4 micro-tile per thread.
// ---------------------------------------------------------------------------
__device__ __forceinline__ void gemm_body(const float* __restrict__ A,
                                          const float* __restrict__ Bm,
                                          float* __restrict__ C) {
  constexpr int N = 512, Kd = 512;
  __shared__ float As[16][68];   // [k][m], padded
  __shared__ float Bs[16][68];   // [k][n]
  const int tid = threadIdx.x;
  const int bm = blockIdx.x * 64;
  const int bn = blockIdx.y * 64;
  const int tr = (tid >> 4) << 2;       // 0..60
  const int tc = (tid & 15) << 2;       // 0..60
  const int ar = tid >> 2;              // A tile row 0..63
  const int ak = (tid & 3) << 2;        // A tile k-col {0,4,8,12}
  const int bk = tid >> 4;              // B tile k-row 0..15
  const int bn4 = (tid & 15) << 2;      // B tile n-col
  float acc[4][4] = {};
  for (int k0 = 0; k0 < Kd; k0 += 16) {
    float4 av = *(const float4*)(A + (size_t)(bm + ar) * Kd + k0 + ak);
    float4 bv = *(const float4*)(Bm + (size_t)(k0 + bk) * N + bn + bn4);
    __syncthreads();
    As[ak + 0][ar] = av.x;
    As[ak + 1][ar] = av.y;
    As[ak + 2][ar] = av.z;
    As[ak + 3][ar] = av.w;
    *(float4*)&Bs[bk][bn4] = bv;
    __syncthreads();
#pragma unroll
    for (int kk = 0; kk < 16; ++kk) {
      float4 a = *(const float4*)&As[kk][tr];
      float4 b = *(const float4*)&Bs[kk][tc];
      const float ai[4] = {a.x, a.y, a.z, a.w};
      const float bj[4] = {b.x, b.y, b.z, b.w};
#pragma unroll
      for (int i = 0; i < 4; ++i)
#pragma unroll
        for (int j = 0; j < 4; ++j) acc[i][j] += ai[i] * bj[j];
    }
  }
#pragma unroll
  for (int i = 0; i < 4; ++i) {
    float4 o4 = {acc[i][0], acc[i][1], acc[i][2], acc[i][3]};
    *(float4*)(C + (size_t)(bm + tr + i) * N + bn + tc) = o4;
  }
}

__global__ __launch_bounds__(256) void gemm3_kernel(
    const float* __restrict__ x,
    const float* __restrict__ Wq, const float* __restrict__ Wk,
    const float* __restrict__ Wv,
    float* __restrict__ qp, float* __restrict__ kp, float* __restrict__ vp) {
  const float* W; float* Cp;
  if (blockIdx.z == 0)      { W = Wq; Cp = qp; }
  else if (blockIdx.z == 1) { W = Wk; Cp = kp; }
  else                      { W = Wv; Cp = vp; }
  gemm_body(x, W, Cp);
}

__global__ __launch_bounds__(256) void gemm1_kernel(
    const float* __restrict__ A, const float* __restrict__ W,
    float* __restrict__ C) {
  gemm_body(A, W, C);
}

// ---------------------------------------------------------------------------
// beta = sigmoid(x @ Wb), Wb:[512,8] -> beta:[B*T,8]
// ---------------------------------------------------------------------------
__global__ __launch_bounds__(256) void beta_kernel(const float* __restrict__ x,
                                                   const float* __restrict__ Wb,
                                                   float* __restrict__ beta) {
  int gid = blockIdx.x * blockDim.x + threadIdx.x;  // 0 .. 16383
  int bt = gid >> 3, h = gid & 7;
  const float* xr = x + (size_t)bt * Dd;
  float s = 0.f;
  for (int d = 0; d < Dd; ++d) s += xr[d] * Wb[d * Hh + h];
  beta[gid] = 1.f / (1.f + expf(-s));
}

// ---------------------------------------------------------------------------
// causal depthwise conv(4) + SiLU (+ optional L2 norm over K, + scale for q)
// ---------------------------------------------------------------------------
__global__ __launch_bounds__(256) void conv_kernel(
    const float* __restrict__ qp, const float* __restrict__ kp,
    const float* __restrict__ vp,
    const float* __restrict__ cwq, const float* __restrict__ cwk,
    const float* __restrict__ cwv,
    float* __restrict__ qc, float* __restrict__ kc, float* __restrict__ vc) {
  const int mode = blockIdx.z;
  const float* pre; const float* cw; float* post;
  if (mode == 0)      { pre = qp; cw = cwq; post = qc; }
  else if (mode == 1) { pre = kp; cw = cwk; post = kc; }
  else                { pre = vp; cw = cwv; post = vc; }

  const int idx = blockIdx.x * 4 + (threadIdx.x >> 6);   // (b,t,h) id, 0..16383
  const int lane = threadIdx.x & 63;
  const int b = idx >> 13;           // /(T*H)
  const int th = idx & 8191;
  const int t = th >> 3;
  const int h = th & 7;
  const int ch = h * 64 + lane;

  float y = 0.f;
#pragma unroll
  for (int i = 0; i < 4; ++i) {
    int tt = t + i - 3;
    if (tt >= 0)
      y += pre[((size_t)(b * Tt + tt)) * HK + ch] * cw[ch * 4 + i];
  }
  // SiLU
  y = y / (1.f + expf(-y));
  if (mode < 2) {
    float ss = y * y;
#pragma unroll
    for (int off = 32; off; off >>= 1) ss += __shfl_xor(ss, off, 64);
    y *= rsqrtf(ss + 1e-6f);
    if (mode == 0) y *= SCALEc;
  }
  post[((size_t)(b * Tt + t)) * HK + ch] = y;
}

// ---------------------------------------------------------------------------
// DPP 16-lane butterfly sum (all 16 lanes of each DPP row end with the total)
// ---------------------------------------------------------------------------
template <int CTRL>
__device__ __forceinline__ float dpp_add(float v) {
  int y = __builtin_amdgcn_update_dpp(0, __float_as_int(v), CTRL, 0xF, 0xF, true);
  return v + __int_as_float(y);
}
__device__ __forceinline__ float reduce16(float x) {
  x = dpp_add<0xB1>(x);   // quad_perm(1,0,3,2)  xor 1
  x = dpp_add<0x4E>(x);   // quad_perm(2,3,0,1)  xor 2
  x = dpp_add<0x141>(x);  // row_half_mirror
  x = dpp_add<0x140>(x);  // row_mirror
  return x;
}

// ---------------------------------------------------------------------------
// sequential IVON delta-rule scan.
// One wave handles 4 v-columns of one (b,h): 64 lanes = 4 v-groups x 16 k-groups,
// each lane holds 4 consecutive k of the S/h/g state for its v-column.
// Reduction over k = 4 local FMAs + 4 DPP adds within a 16-lane row.
// Depth-8 register prefetch pipeline hides the L2-miss/L3 load latency
// (conv wrote q/k/v on other XCDs; ~500-700 cy round trip).
// ---------------------------------------------------------------------------
#define IVON_STEP(kv, qv, vv, bt, tidx)                                        \
  do {                                                                         \
    float pl = kv.x * S0 + kv.y * S1 + kv.z * S2 + kv.w * S3;                  \
    float pred = reduce16(pl);                                                 \
    float diff = pred - (vv);                                                  \
    float lrb = LRc * (bt);                                                    \
    float gr;                                                                  \
    gr = kv.x * diff; g0 = B1c * g0 + 0.1f * gr;                               \
    h0 = B2c * h0 + 0.001f * (gr * gr);                                        \
    S0 -= lrb * g0 * __builtin_amdgcn_rcpf(h0 + 1.f);                          \
    gr = kv.y * diff; g1 = B1c * g1 + 0.1f * gr;                               \
    h1 = B2c * h1 + 0.001f * (gr * gr);                                        \
    S1 -= lrb * g1 * __builtin_amdgcn_rcpf(h1 + 1.f);                          \
    gr = kv.z * diff; g2 = B1c * g2 + 0.1f * gr;                               \
    h2 = B2c * h2 + 0.001f * (gr * gr);                                        \
    S2 -= lrb * g2 * __builtin_amdgcn_rcpf(h2 + 1.f);                          \
    gr = kv.w * diff; g3 = B1c * g3 + 0.1f * gr;                               \
    h3 = B2c * h3 + 0.001f * (gr * gr);                                        \
    S3 -= lrb * g3 * __builtin_amdgcn_rcpf(h3 + 1.f);                          \
    float ol = qv.x * S0 + qv.y * S1 + qv.z * S2 + qv.w * S3;                  \
    float ov = reduce16(ol);                                                   \
    if (kg == 0) op[(size_t)(tidx)*HK] = ov;                                   \
  } while (0)

#define PD 8   // prefetch depth (steps)

__global__ __launch_bounds__(64) void scan_kernel(
    const float* __restrict__ qc, const float* __restrict__ kc,
    const float* __restrict__ vc, const float* __restrict__ beta,
    float* __restrict__ o) {
  const int lane = threadIdx.x;       // 0..63
  const int vg = lane >> 4;           // 0..3  (v within this wave's group of 4)
  const int kg = lane & 15;           // 0..15 (k-group; 4 k per lane)
  const int bid = blockIdx.x;         // 0..255
  const int vq = bid >> 4;            // 0..15
  const int bh = bid & 15;            // same XCD for all vq of this bh
  const int b = bh >> 3, h = bh & 7;
  const int v = vq * 4 + vg;

  const size_t base = ((size_t)b * Tt) * HK + h * 64;
  const float* kp = kc + base + kg * 4;
  const float* qp = qc + base + kg * 4;
  const float* vp = vc + base + v;
  const float* bp = beta + ((size_t)b * Tt) * Hh + h;
  float* op = o + base + v;

  float S0 = 0, S1 = 0, S2 = 0, S3 = 0;
  float h0 = 0, h1 = 0, h2 = 0, h3 = 0;
  float g0 = 0, g1 = 0, g2 = 0, g3 = 0;

  // depth-PD register prefetch (fully unrolled -> static indexing -> registers)
  float4 kb[PD], qb[PD];
  float  vb[PD], bb[PD];
#pragma unroll
  for (int i = 0; i < PD; ++i) {
    kb[i] = *(const float4*)(kp + (size_t)i * HK);
    qb[i] = *(const float4*)(qp + (size_t)i * HK);
    vb[i] = vp[(size_t)i * HK];
    bb[i] = bp[(size_t)i * Hh];
  }

  for (int t0 = 0; t0 < Tt; t0 += PD) {
#pragma unroll
    for (int i = 0; i < PD; ++i) {
      const int t = t0 + i;
      float4 kv = kb[i], qv = qb[i];
      float  vv = vb[i], bt = bb[i];
      int tp = t + PD; if (tp >= Tt) tp = Tt - 1;   // clamped dummy prefetch
      kb[i] = *(const float4*)(kp + (size_t)tp * HK);
      qb[i] = *(const float4*)(qp + (size_t)tp * HK);
      vb[i] = vp[(size_t)tp * HK];
      bb[i] = bp[(size_t)tp * Hh];
      IVON_STEP(kv, qv, vv, bt, t);
    }
  }
}

// ---------------------------------------------------------------------------
// RMSNorm over V=64 (in-place), * rms_w
// ---------------------------------------------------------------------------
__global__ __launch_bounds__(256) void rmsnorm_kernel(float* __restrict__ o,
                                                      const float* __restrict__ rmsw) {
  const int idx = blockIdx.x * 4 + (threadIdx.x >> 6);  // (b,t,h), 0..16383
  const int lane = threadIdx.x & 63;
  float* p = o + (size_t)idx * 64;
  float y = p[lane];
  float ss = y * y;
#pragma unroll
  for (int off = 32; off; off >>= 1) ss += __shfl_xor(ss, off, 64);
  y = y * rsqrtf(ss * (1.f / 64.f) + 1e-5f) * rmsw[lane];
  p[lane] = y;
}

// ---------------------------------------------------------------------------
extern "C" void kernel_launch(void* const* d_in, const int* in_sizes, int n_in,
                              void* d_out, int out_size, void* d_ws, size_t ws_size,
                              hipStream_t stream) {
  const float* x    = (const float*)d_in[0];
  const float* Wq   = (const float*)d_in[1];
  const float* Wk   = (const float*)d_in[2];
  const float* Wv   = (const float*)d_in[3];
  const float* Wb   = (const float*)d_in[4];
  const float* cwq  = (const float*)d_in[5];
  const float* cwk  = (const float*)d_in[6];
  const float* cwv  = (const float*)d_in[7];
  const float* rmsw = (const float*)d_in[8];
  const float* Wo   = (const float*)d_in[9];
  float* out = (float*)d_out;
  float* ws  = (float*)d_ws;

  const size_t SZ = (size_t)BT * HK;   // 1,048,576 floats
  float* qp   = ws;            // pre-conv q   (later reused as scan output)
  float* kp   = ws + 1 * SZ;
  float* vp   = ws + 2 * SZ;
  float* qc   = ws + 3 * SZ;
  float* kc   = ws + 4 * SZ;
  float* vc   = ws + 5 * SZ;
  float* beta = ws + 6 * SZ;   // 16384 floats
  float* on   = qp;            // scan output / rmsnorm in-place (qp dead then)

  // 1. projections q,k,v
  gemm3_kernel<<<dim3(BT / 64, HK / 64, 3), 256, 0, stream>>>(x, Wq, Wk, Wv, qp, kp, vp);
  // 2. beta
  beta_kernel<<<dim3(BT * Hh / 256), 256, 0, stream>>>(x, Wb, beta);
  // 3. conv + silu + l2norm
  conv_kernel<<<dim3(Bb * Tt * Hh / 4, 1, 3), 256, 0, stream>>>(
      qp, kp, vp, cwq, cwk, cwv, qc, kc, vc);
  // 4. sequential scan (DPP 16-lane reduce, 4 v per wave, depth-8 prefetch)
  scan_kernel<<<dim3(Bb * Hh * (Vv / 4) * (Vv / 16) / 4), 64, 0, stream>>>(
      qc, kc, vc, beta, on);
  // 5. RMSNorm (in-place)
  rmsnorm_kernel<<<dim3(Bb * Tt * Hh / 4), 256, 0, stream>>>(on, rmsw);
  // 6. output projection
  gemm1_kernel<<<dim3(BT / 64, HK / 64, 1), 256, 0, stream>>>(on, Wo, out);
}

// Round 5
// 303.241 us; speedup vs baseline: 2.5986x; 1.0981x over previous
//
#include <hip/hip_runtime.h>
#include <hip/hip_bf16.h>
#include <math.h>

// Dims (compile-time constants for this problem)
#define Bb 2
#define Tt 1024
#define Dd 512
#define Hh 8
#define Kk 64
#define Vv 64
#define BT (Bb*Tt)          // 2048
#define HK (Hh*Kk)          // 512

// hyperparams
#define B1c 0.9f
#define B2c 0.999f
#define LRc 1e-3f
#define SCALEc 0.125f       // 64^-0.5

// ---------------------------------------------------------------------------
// fp32 tiled GEMM: C[M,N] = A[M,K] @ W[K,N], M=2048, N=512, K=512
// BM=BN=64, BK=16, 256 threads, 4x4 micro-tile per thread.
// ---------------------------------------------------------------------------
__device__ __forceinline__ void gemm_body(const float* __restrict__ A,
                                          const float* __restrict__ Bm,
                                          float* __restrict__ C) {
  constexpr int N = 512, Kd = 512;
  __shared__ float As[16][68];   // [k][m], padded
  __shared__ float Bs[16][68];   // [k][n]
  const int tid = threadIdx.x;
  const int bm = blockIdx.x * 64;
  const int bn = blockIdx.y * 64;
  const int tr = (tid >> 4) << 2;       // 0..60
  const int tc = (tid & 15) << 2;       // 0..60
  const int ar = tid >> 2;              // A tile row 0..63
  const int ak = (tid & 3) << 2;        // A tile k-col {0,4,8,12}
  const int bk = tid >> 4;              // B tile k-row 0..15
  const int bn4 = (tid & 15) << 2;      // B tile n-col
  float acc[4][4] = {};
  for (int k0 = 0; k0 < Kd; k0 += 16) {
    float4 av = *(const float4*)(A + (size_t)(bm + ar) * Kd + k0 + ak);
    float4 bv = *(const float4*)(Bm + (size_t)(k0 + bk) * N + bn + bn4);
    __syncthreads();
    As[ak + 0][ar] = av.x;
    As[ak + 1][ar] = av.y;
    As[ak + 2][ar] = av.z;
    As[ak + 3][ar] = av.w;
    *(float4*)&Bs[bk][bn4] = bv;
    __syncthreads();
#pragma unroll
    for (int kk = 0; kk < 16; ++kk) {
      float4 a = *(const float4*)&As[kk][tr];
      float4 b = *(const float4*)&Bs[kk][tc];
      const float ai[4] = {a.x, a.y, a.z, a.w};
      const float bj[4] = {b.x, b.y, b.z, b.w};
#pragma unroll
      for (int i = 0; i < 4; ++i)
#pragma unroll
        for (int j = 0; j < 4; ++j) acc[i][j] += ai[i] * bj[j];
    }
  }
#pragma unroll
  for (int i = 0; i < 4; ++i) {
    float4 o4 = {acc[i][0], acc[i][1], acc[i][2], acc[i][3]};
    *(float4*)(C + (size_t)(bm + tr + i) * N + bn + tc) = o4;
  }
}

__global__ __launch_bounds__(256) void gemm3_kernel(
    const float* __restrict__ x,
    const float* __restrict__ Wq, const float* __restrict__ Wk,
    const float* __restrict__ Wv,
    float* __restrict__ qp, float* __restrict__ kp, float* __restrict__ vp) {
  const float* W; float* Cp;
  if (blockIdx.z == 0)      { W = Wq; Cp = qp; }
  else if (blockIdx.z == 1) { W = Wk; Cp = kp; }
  else                      { W = Wv; Cp = vp; }
  gemm_body(x, W, Cp);
}

__global__ __launch_bounds__(256) void gemm1_kernel(
    const float* __restrict__ A, const float* __restrict__ W,
    float* __restrict__ C) {
  gemm_body(A, W, C);
}

// ---------------------------------------------------------------------------
// beta = sigmoid(x @ Wb), Wb:[512,8] -> beta:[B*T,8]
// ---------------------------------------------------------------------------
__global__ __launch_bounds__(256) void beta_kernel(const float* __restrict__ x,
                                                   const float* __restrict__ Wb,
                                                   float* __restrict__ beta) {
  int gid = blockIdx.x * blockDim.x + threadIdx.x;  // 0 .. 16383
  int bt = gid >> 3, h = gid & 7;
  const float* xr = x + (size_t)bt * Dd;
  float s = 0.f;
  for (int d = 0; d < Dd; ++d) s += xr[d] * Wb[d * Hh + h];
  beta[gid] = 1.f / (1.f + expf(-s));
}

// ---------------------------------------------------------------------------
// causal depthwise conv(4) + SiLU (+ optional L2 norm over K, + scale for q)
// ---------------------------------------------------------------------------
__global__ __launch_bounds__(256) void conv_kernel(
    const float* __restrict__ qp, const float* __restrict__ kp,
    const float* __restrict__ vp,
    const float* __restrict__ cwq, const float* __restrict__ cwk,
    const float* __restrict__ cwv,
    float* __restrict__ qc, float* __restrict__ kc, float* __restrict__ vc) {
  const int mode = blockIdx.z;
  const float* pre; const float* cw; float* post;
  if (mode == 0)      { pre = qp; cw = cwq; post = qc; }
  else if (mode == 1) { pre = kp; cw = cwk; post = kc; }
  else                { pre = vp; cw = cwv; post = vc; }

  const int idx = blockIdx.x * 4 + (threadIdx.x >> 6);   // (b,t,h) id, 0..16383
  const int lane = threadIdx.x & 63;
  const int b = idx >> 13;           // /(T*H)
  const int th = idx & 8191;
  const int t = th >> 3;
  const int h = th & 7;
  const int ch = h * 64 + lane;

  float y = 0.f;
#pragma unroll
  for (int i = 0; i < 4; ++i) {
    int tt = t + i - 3;
    if (tt >= 0)
      y += pre[((size_t)(b * Tt + tt)) * HK + ch] * cw[ch * 4 + i];
  }
  // SiLU
  y = y / (1.f + expf(-y));
  if (mode < 2) {
    float ss = y * y;
#pragma unroll
    for (int off = 32; off; off >>= 1) ss += __shfl_xor(ss, off, 64);
    y *= rsqrtf(ss + 1e-6f);
    if (mode == 0) y *= SCALEc;
  }
  post[((size_t)(b * Tt + t)) * HK + ch] = y;
}

// ---------------------------------------------------------------------------
// 64-lane butterfly sum, all-VALU-pipe:
// 4 DPP adds (xor 1,2,4,8) + permlane16_swap (xor 16) + permlane32_swap (xor 32)
// ---------------------------------------------------------------------------
template <int CTRL>
__device__ __forceinline__ float dpp_add(float v) {
  int y = __builtin_amdgcn_update_dpp(0, __float_as_int(v), CTRL, 0xF, 0xF, true);
  return v + __int_as_float(y);
}

typedef unsigned uint2_t __attribute__((ext_vector_type(2)));

__device__ __forceinline__ float xor16_add(float x) {
#if __has_builtin(__builtin_amdgcn_permlane16_swap)
  uint2_t r = __builtin_amdgcn_permlane16_swap(__float_as_uint(x), __float_as_uint(x),
                                               false, false);
  return __uint_as_float(r.x) + __uint_as_float(r.y);
#else
  int y = __builtin_amdgcn_ds_swizzle(__float_as_int(x), 0x401F);  // xor 16
  return x + __int_as_float(y);
#endif
}

__device__ __forceinline__ float xor32_add(float x) {
#if __has_builtin(__builtin_amdgcn_permlane32_swap)
  uint2_t r = __builtin_amdgcn_permlane32_swap(__float_as_uint(x), __float_as_uint(x),
                                               false, false);
  return __uint_as_float(r.x) + __uint_as_float(r.y);
#else
  return x + __shfl_xor(x, 32, 64);
#endif
}

__device__ __forceinline__ float reduce64(float x) {
  x = dpp_add<0xB1>(x);   // quad_perm xor 1
  x = dpp_add<0x4E>(x);   // quad_perm xor 2
  x = dpp_add<0x141>(x);  // row_half_mirror (xor 4)
  x = dpp_add<0x140>(x);  // row_mirror (xor 8)
  x = xor16_add(x);
  x = xor32_add(x);
  return x;
}

// ---------------------------------------------------------------------------
// sequential IVON delta-rule scan.
// One wave per output column (b,h,v); lane = k. State S,h,g = 3 VGPRs/lane.
// 256 blocks x 4 waves = 1024 waves = 4 per CU, one per SIMD.
// Pred/o reduction = 64-lane VALU butterfly (DPP + permlane swaps).
// Depth-8 register prefetch hides the ~700 cy cross-XCD L2/L3 load latency.
// ---------------------------------------------------------------------------
#define PD 8   // prefetch depth (steps)

__global__ __launch_bounds__(256) void scan_kernel(
    const float* __restrict__ qc, const float* __restrict__ kc,
    const float* __restrict__ vc, const float* __restrict__ beta,
    float* __restrict__ o) {
  const int lane = threadIdx.x & 63;
  const int widx = threadIdx.x >> 6;   // 0..3 (v within block)
  const int bid = blockIdx.x;          // 0..255
  const int vq = bid >> 4;             // 0..15
  const int bh = bid & 15;             // bid%8 == bh%8 -> same XCD per (b,h)
  const int b = bh >> 3, h = bh & 7;
  const int v = vq * 4 + widx;         // 0..63

  const size_t base = ((size_t)b * Tt) * HK + h * 64;
  const float* kp = kc + base + lane;
  const float* qp = qc + base + lane;
  const float* vp = vc + base + v;
  const float* bp = beta + ((size_t)b * Tt) * Hh + h;
  float* op = o + base + v;

  float S = 0.f, hs = 0.f, g = 0.f;

  // depth-PD register prefetch (fully unrolled -> static indexing -> registers)
  float kb[PD], qb[PD], vb[PD], bb[PD];
#pragma unroll
  for (int i = 0; i < PD; ++i) {
    kb[i] = kp[(size_t)i * HK];
    qb[i] = qp[(size_t)i * HK];
    vb[i] = vp[(size_t)i * HK];
    bb[i] = bp[(size_t)i * Hh];
  }

  for (int t0 = 0; t0 < Tt; t0 += PD) {
#pragma unroll
    for (int i = 0; i < PD; ++i) {
      const int t = t0 + i;
      const float kv = kb[i], qv = qb[i], vv = vb[i], bt = bb[i];
      int tp = t + PD; if (tp >= Tt) tp = Tt - 1;   // clamped dummy prefetch
      kb[i] = kp[(size_t)tp * HK];
      qb[i] = qp[(size_t)tp * HK];
      vb[i] = vp[(size_t)tp * HK];
      bb[i] = bp[(size_t)tp * Hh];

      float pred = reduce64(kv * S);
      float diff = pred - vv;
      float gr = kv * diff;
      g = B1c * g + 0.1f * gr;
      hs = B2c * hs + 0.001f * (gr * gr);
      S -= (LRc * bt) * g * __builtin_amdgcn_rcpf(hs + 1.f);
      float ov = reduce64(qv * S);
      if (lane == 0) op[(size_t)t * HK] = ov;
    }
  }
}

// ---------------------------------------------------------------------------
// RMSNorm over V=64 (in-place), * rms_w
// ---------------------------------------------------------------------------
__global__ __launch_bounds__(256) void rmsnorm_kernel(float* __restrict__ o,
                                                      const float* __restrict__ rmsw) {
  const int idx = blockIdx.x * 4 + (threadIdx.x >> 6);  // (b,t,h), 0..16383
  const int lane = threadIdx.x & 63;
  float* p = o + (size_t)idx * 64;
  float y = p[lane];
  float ss = y * y;
#pragma unroll
  for (int off = 32; off; off >>= 1) ss += __shfl_xor(ss, off, 64);
  y = y * rsqrtf(ss * (1.f / 64.f) + 1e-5f) * rmsw[lane];
  p[lane] = y;
}

// ---------------------------------------------------------------------------
extern "C" void kernel_launch(void* const* d_in, const int* in_sizes, int n_in,
                              void* d_out, int out_size, void* d_ws, size_t ws_size,
                              hipStream_t stream) {
  const float* x    = (const float*)d_in[0];
  const float* Wq   = (const float*)d_in[1];
  const float* Wk   = (const float*)d_in[2];
  const float* Wv   = (const float*)d_in[3];
  const float* Wb   = (const float*)d_in[4];
  const float* cwq  = (const float*)d_in[5];
  const float* cwk  = (const float*)d_in[6];
  const float* cwv  = (const float*)d_in[7];
  const float* rmsw = (const float*)d_in[8];
  const float* Wo   = (const float*)d_in[9];
  float* out = (float*)d_out;
  float* ws  = (float*)d_ws;

  const size_t SZ = (size_t)BT * HK;   // 1,048,576 floats
  float* qp   = ws;            // pre-conv q   (later reused as scan output)
  float* kp   = ws + 1 * SZ;
  float* vp   = ws + 2 * SZ;
  float* qc   = ws + 3 * SZ;
  float* kc   = ws + 4 * SZ;
  float* vc   = ws + 5 * SZ;
  float* beta = ws + 6 * SZ;   // 16384 floats
  float* on   = qp;            // scan output / rmsnorm in-place (qp dead then)

  // 1. projections q,k,v
  gemm3_kernel<<<dim3(BT / 64, HK / 64, 3), 256, 0, stream>>>(x, Wq, Wk, Wv, qp, kp, vp);
  // 2. beta
  beta_kernel<<<dim3(BT * Hh / 256), 256, 0, stream>>>(x, Wb, beta);
  // 3. conv + silu + l2norm
  conv_kernel<<<dim3(Bb * Tt * Hh / 4, 1, 3), 256, 0, stream>>>(
      qp, kp, vp, cwq, cwk, cwv, qc, kc, vc);
  // 4. sequential scan: 256 blocks x 4 waves, one v-column per wave (v = vq*4+widx)
  scan_kernel<<<dim3(Bb * Hh * (Vv / 4)), 256, 0, stream>>>(
      qc, kc, vc, beta, on);
  // 5. RMSNorm (in-place)
  rmsnorm_kernel<<<dim3(Bb * Tt * Hh / 4), 256, 0, stream>>>(on, rmsw);
  // 6. output projection
  gemm1_kernel<<<dim3(BT / 64, HK / 64, 1), 256, 0, stream>>>(on, Wo, out);
}